// Round 1
// baseline (193.122 us; speedup 1.0000x reference)
//
#include <hip/hip_runtime.h>
#include <hip/hip_bf16.h>

#define DEG        16
#define IN_FEATS   256
#define NUM_HEADS  4
#define OUT_FEATS  64
#define HF         256
#define NEG_SLOPE  0.2f

#define CPITCH 264     // 256 + 8 (epilogue store-transpose pitch)

typedef __attribute__((ext_vector_type(8))) short  short8;
typedef __attribute__((ext_vector_type(4))) float  floatx4;
typedef unsigned short ushortT;

__device__ __forceinline__ unsigned short f2bf(float f) {
    union { float f; unsigned u; } v; v.f = f;
    unsigned r = v.u + 0x7fffu + ((v.u >> 16) & 1u);   // round-to-nearest-even
    return (unsigned short)(r >> 16);
}
// bf16 unpack: guaranteed 1 VALU each (shift / and)
__device__ __forceinline__ float bf_lo(unsigned u) {
    union { unsigned x; float f; } v; v.x = u << 16; return v.f;
}
__device__ __forceinline__ float bf_hi(unsigned u) {
    union { unsigned x; float f; } v; v.x = u & 0xffff0000u; return v.f;
}
// packed fp32x2 -> bf16x2 (manual RTNE pack; verified absmax since round 2)
__device__ __forceinline__ unsigned cvt2(float lo, float hi) {
    return (unsigned)f2bf(lo) | ((unsigned)f2bf(hi) << 16);
}

// ---------------------------------------------------------------------------
// Kernel 0: Wt[n][k] = bf16(W[k][n])  (256x256, tiny)
// ---------------------------------------------------------------------------
__global__ __launch_bounds__(256) void conv_wt(
    const float* __restrict__ W, ushortT* __restrict__ Wt)
{
    int n = blockIdx.x;
    int k = threadIdx.x;
    Wt[n * 256 + k] = f2bf(W[k * 256 + n]);
}

// ---------------------------------------------------------------------------
// Kernel 1: h = feat @ W via MFMA bf16, fp32->bf16 conversion FUSED into the
// A-staging (packed cvt + swizzled ds_write).  Tile 64x256, full K=256,
// single staging barrier.  B: direct global->VGPR per wave (L2-resident Wt),
// 1-step prefetch.  Epilogue: fused attention scores + row-major bf16 Hb
// store via LDS transpose.  BYTE-IDENTICAL to the round-4/5 verified kernel.
// ---------------------------------------------------------------------------
__global__ __launch_bounds__(256, 3) void gat_gemm_fused(
    const float* __restrict__ feat,           // fp32 [M,256]
    const ushortT* __restrict__ Bt,           // Wt bf16 [n=256][k=256]
    const float* __restrict__ attn_l,         // [256]
    const float* __restrict__ attn_r,         // [256]
    ushortT* __restrict__ Hb,                 // h bf16 [M,256]
    float* __restrict__ arow,                 // [M,4]
    float* __restrict__ acol,                 // [M,4]
    int M)
{
    // As: 64 rows x 32 chunks x 16B = 32 KB (XOR-swizzled). Cs overlays.
    __shared__ __align__(16) ushortT SMEM[64 * CPITCH];
    ushortT* As = SMEM;
    ushortT* Cs = SMEM;

    const int tid  = threadIdx.x;
    const int wave = tid >> 6;       // == head
    const int lane = tid & 63;
    const int l15  = lane & 15;
    const int quad = lane >> 4;
    const int rowBase = blockIdx.x * 64;

    // ---- Prefetch B for ks=0 (independent of LDS staging).
    short8 bbuf[2][4];
    #pragma unroll
    for (int ni = 0; ni < 4; ++ni)
        bbuf[0][ni] = *(const short8*)&Bt[(wave * 64 + ni * 16 + l15) * 256 + quad * 8];

    // ---- Stage A: 64 rows x 256 cols fp32 -> bf16 swizzled LDS.
    // 4096 float4s total; 2 passes x 8 per thread (8 loads in flight/pass).
    // Layout: 16B chunk cg of row r stored at chunk (cg ^ (r&7))  [verified r4].
    #pragma unroll
    for (int pass = 0; pass < 2; ++pass) {
        float4 v[8];
        #pragma unroll
        for (int i = 0; i < 8; ++i) {
            int id  = pass * 2048 + i * 256 + tid;   // flat float4 index
            int row = id >> 6;                        // 64 float4 per row
            int c4  = id & 63;
            int gr  = rowBase + row; if (gr > M - 1) gr = M - 1;
            v[i] = *(const float4*)&feat[(size_t)gr * 256 + c4 * 4];
        }
        #pragma unroll
        for (int i = 0; i < 8; ++i) {
            int id   = pass * 2048 + i * 256 + tid;
            int row  = id >> 6;
            int c4   = id & 63;
            int cg   = c4 >> 1;                       // 16B chunk col (0..31)
            int half = c4 & 1;
            uint2 w = make_uint2(cvt2(v[i].x, v[i].y), cvt2(v[i].z, v[i].w));
            *(uint2*)&As[row * 256 + ((cg ^ (row & 7)) << 3) + half * 4] = w;
        }
    }

    __syncthreads();

    floatx4 acc[4][4] = {};

    #pragma unroll
    for (int ks = 0; ks < 8; ++ks) {
        if (ks < 7) {
            #pragma unroll
            for (int ni = 0; ni < 4; ++ni)
                bbuf[(ks + 1) & 1][ni] = *(const short8*)
                    &Bt[(wave * 64 + ni * 16 + l15) * 256 + (ks + 1) * 32 + quad * 8];
        }
        short8 af[4];
        #pragma unroll
        for (int mi = 0; mi < 4; ++mi) {
            int row = mi * 16 + l15;
            int q   = ks * 4 + quad;
            int cst = q ^ (row & 7);
            af[mi] = *(const short8*)&As[row * 256 + cst * 8];
        }
        #pragma unroll
        for (int mi = 0; mi < 4; ++mi)
            #pragma unroll
            for (int ni = 0; ni < 4; ++ni)
                acc[mi][ni] = __builtin_amdgcn_mfma_f32_16x16x32_bf16(
                    af[mi], bbuf[ks & 1][ni], acc[mi][ni], 0, 0, 0);
    }

    // ---- Epilogue A: attention scores (wave == head).
    float al[4], ar[4];
    #pragma unroll
    for (int ni = 0; ni < 4; ++ni) {
        al[ni] = attn_l[wave * 64 + ni * 16 + l15];
        ar[ni] = attn_r[wave * 64 + ni * 16 + l15];
    }
    #pragma unroll
    for (int mi = 0; mi < 4; ++mi) {
        #pragma unroll
        for (int reg = 0; reg < 4; ++reg) {
            float pl = 0.f, pr = 0.f;
            #pragma unroll
            for (int ni = 0; ni < 4; ++ni) {
                pl = fmaf(acc[mi][ni][reg], al[ni], pl);
                pr = fmaf(acc[mi][ni][reg], ar[ni], pr);
            }
            #pragma unroll
            for (int off = 8; off >= 1; off >>= 1) {
                pl += __shfl_xor(pl, off, 64);   // stays within 16-lane quad
                pr += __shfl_xor(pr, off, 64);
            }
            if (l15 == 0) {
                int gr = rowBase + mi * 16 + quad * 4 + reg;
                if (gr < M) {
                    arow[gr * NUM_HEADS + wave] = pl;
                    acol[gr * NUM_HEADS + wave] = pr;
                }
            }
        }
    }

    __syncthreads();   // all As reads complete before Cs overlay

    // ---- Epilogue B: h -> bf16, coalesced row-major store via LDS transpose.
    #pragma unroll
    for (int mi = 0; mi < 4; ++mi)
        #pragma unroll
        for (int ni = 0; ni < 4; ++ni)
            #pragma unroll
            for (int reg = 0; reg < 4; ++reg)
                Cs[(mi * 16 + quad * 4 + reg) * CPITCH + wave * 64 + ni * 16 + l15] =
                    f2bf(acc[mi][ni][reg]);
    __syncthreads();

    #pragma unroll
    for (int i = 0; i < 8; ++i) {
        int f  = tid + 256 * i;
        int r  = f >> 5;
        int c8 = (f & 31) << 3;
        int gr = rowBase + r;
        if (gr < M) {
            uint4 v = *(const uint4*)&Cs[r * CPITCH + c8];
            *(uint4*)&Hb[(size_t)gr * HF + c8] = v;
        }
    }
}

// ---------------------------------------------------------------------------
// Kernel 2 (v4): ONE WAVE PER NODE, DUAL-EDGE uint4 GATHER.
// Change vs v3: inner loop processes 2 edges per iteration — lanes 0-31
// gather edge 2j, lanes 32-63 gather edge 2j+1, 16 B/lane dwordx4 loads
// (halves VMEM instruction count and bpermute count, same bytes).
// Softmax phase unchanged (verified layout: lane = head*16 + edge).
// ---------------------------------------------------------------------------
__global__ __launch_bounds__(256) void gat_aggregate4(
    const ushortT* __restrict__ Hb,          // bf16 [N,256]
    const float* __restrict__ arow,          // [N,4]
    const float* __restrict__ acol,          // [N,4]
    const int* __restrict__ col_ind,         // [N*16]
    float* __restrict__ out,                 // [N,256] fp32
    int N)
{
    const int tid  = threadIdx.x;
    const int wave = tid >> 6;
    const int lane = tid & 63;
    const int n    = blockIdx.x * 4 + wave;
    if (n >= N) return;

    // ---- Softmax phase: lane = head(hd16)*16 + edge(j16)  [unchanged].
    const int j16  = lane & 15;
    const int hd16 = lane >> 4;

    int   src_e = col_ind[n * DEG + j16];
    float e = arow[n * NUM_HEADS + hd16] + acol[src_e * NUM_HEADS + hd16];
    e = (e > 0.f) ? e : NEG_SLOPE * e;

    float m = e;
    #pragma unroll
    for (int off = 8; off >= 1; off >>= 1)
        m = fmaxf(m, __shfl_xor(m, off, 16));
    float ex = __expf(e - m);
    float s = ex;
    #pragma unroll
    for (int off = 8; off >= 1; off >>= 1)
        s += __shfl_xor(s, off, 16);
    float alpha = ex / s;                  // alpha[head=hd16][edge=j16]

    // ---- Aggregation phase: dual-edge per iteration.
    // Lane covers feats l32*8 .. l32*8+7  (head = l32>>3).
    // half 0 accumulates even edges, half 1 odd edges; combine at the end.
    const int l32     = lane & 31;
    const int half    = lane >> 5;
    const int headSel = (l32 >> 3) << 4;   // head*16, for alpha bpermute

    float acc[8] = {};

    #pragma unroll
    for (int j = 0; j < 8; ++j) {
        int   ep = (j << 1) + half;                         // edge 0..15
        int   sj = __shfl(src_e, ep, 64);                   // col_ind[n*16+ep]
        float a  = __shfl(alpha, headSel + ep, 64);         // alpha[head][ep]
        uint4 v  = *(const uint4*)&Hb[(size_t)sj * HF + l32 * 8];  // 16 B/lane
        acc[0] = fmaf(a, bf_lo(v.x), acc[0]);
        acc[1] = fmaf(a, bf_hi(v.x), acc[1]);
        acc[2] = fmaf(a, bf_lo(v.y), acc[2]);
        acc[3] = fmaf(a, bf_hi(v.y), acc[3]);
        acc[4] = fmaf(a, bf_lo(v.z), acc[4]);
        acc[5] = fmaf(a, bf_hi(v.z), acc[5]);
        acc[6] = fmaf(a, bf_lo(v.w), acc[6]);
        acc[7] = fmaf(a, bf_hi(v.w), acc[7]);
    }

    // Combine even/odd halves: after xor-add both halves hold full sums.
    #pragma unroll
    for (int i = 0; i < 8; ++i)
        acc[i] += __shfl_xor(acc[i], 32, 64);

    // Store: lane (l32, half) writes feats l32*8 + half*4 .. +3.
    // Static indexing only (avoid runtime-indexed array -> scratch).
    float4 o;
    if (half == 0) o = make_float4(acc[0], acc[1], acc[2], acc[3]);
    else           o = make_float4(acc[4], acc[5], acc[6], acc[7]);
    *(float4*)&out[(size_t)n * HF + l32 * 8 + half * 4] = o;
}

// ---------------------------------------------------------------------------
extern "C" void kernel_launch(void* const* d_in, const int* in_sizes, int n_in,
                              void* d_out, int out_size, void* d_ws, size_t ws_size,
                              hipStream_t stream) {
    // Inputs: row_ptr, col_ind, col_ptr, row_ind, feat, W, attn_l, attn_r
    const int*   col_ind = (const int*)  d_in[1];
    const float* feat    = (const float*)d_in[4];
    const float* W       = (const float*)d_in[5];
    const float* attn_l  = (const float*)d_in[6];
    const float* attn_r  = (const float*)d_in[7];
    float* out = (float*)d_out;

    const int N = in_sizes[0] - 1;   // 50000

    // ws: Hb bf16 [N*256] | arow f32 [N*4] | acol f32 [N*4] | Wt bf16 [64K]
    ushortT* Hb   = (ushortT*)d_ws;
    float*   arow = (float*)(Hb + (size_t)N * HF);
    float*   acol = arow + (size_t)N * NUM_HEADS;
    ushortT* Wt   = (ushortT*)(acol + (size_t)N * NUM_HEADS);

    conv_wt<<<256, 256, 0, stream>>>(W, Wt);

    dim3 ggrid((N + 63) / 64);
    gat_gemm_fused<<<ggrid, 256, 0, stream>>>(feat, Wt, attn_l, attn_r,
                                              Hb, arow, acol, N);

    gat_aggregate4<<<(N + 3) / 4, 256, 0, stream>>>(Hb, arow, acol, col_ind, out, N);
}

// Round 2
// 191.132 us; speedup vs baseline: 1.0104x; 1.0104x over previous
//
#include <hip/hip_runtime.h>
#include <hip/hip_bf16.h>

#define DEG        16
#define IN_FEATS   256
#define NUM_HEADS  4
#define OUT_FEATS  64
#define HF         256
#define NEG_SLOPE  0.2f

#define CPITCH 264     // 256 + 8 (epilogue store-transpose pitch)

typedef __attribute__((ext_vector_type(8))) short  short8;
typedef __attribute__((ext_vector_type(4))) float  floatx4;
typedef unsigned short ushortT;

__device__ __forceinline__ unsigned short f2bf(float f) {
    union { float f; unsigned u; } v; v.f = f;
    unsigned r = v.u + 0x7fffu + ((v.u >> 16) & 1u);   // round-to-nearest-even
    return (unsigned short)(r >> 16);
}
// bf16 unpack: guaranteed 1 VALU each (shift / and)
__device__ __forceinline__ float bf_lo(unsigned u) {
    union { unsigned x; float f; } v; v.x = u << 16; return v.f;
}
__device__ __forceinline__ float bf_hi(unsigned u) {
    union { unsigned x; float f; } v; v.x = u & 0xffff0000u; return v.f;
}
// packed fp32x2 -> bf16x2 (manual RTNE pack; verified absmax since round 2)
__device__ __forceinline__ unsigned cvt2(float lo, float hi) {
    return (unsigned)f2bf(lo) | ((unsigned)f2bf(hi) << 16);
}

// ---------------------------------------------------------------------------
// Kernel 0: Wt[n][k] = bf16(W[k][n])  (256x256, tiny)
// ---------------------------------------------------------------------------
__global__ __launch_bounds__(256) void conv_wt(
    const float* __restrict__ W, ushortT* __restrict__ Wt)
{
    int n = blockIdx.x;
    int k = threadIdx.x;
    Wt[n * 256 + k] = f2bf(W[k * 256 + n]);
}

// ---------------------------------------------------------------------------
// Kernel 1: h = feat @ W via MFMA bf16, fp32->bf16 conversion FUSED into the
// A-staging (packed cvt + swizzled ds_write).  Tile 64x256, full K=256,
// single staging barrier.  B: direct global->VGPR per wave (L2-resident Wt),
// 1-step prefetch.  Epilogue: fused attention scores + row-major bf16 Hb
// store via LDS transpose.  BYTE-IDENTICAL to the round-4/5 verified kernel.
// ---------------------------------------------------------------------------
__global__ __launch_bounds__(256, 3) void gat_gemm_fused(
    const float* __restrict__ feat,           // fp32 [M,256]
    const ushortT* __restrict__ Bt,           // Wt bf16 [n=256][k=256]
    const float* __restrict__ attn_l,         // [256]
    const float* __restrict__ attn_r,         // [256]
    ushortT* __restrict__ Hb,                 // h bf16 [M,256]
    float* __restrict__ arow,                 // [M,4]
    float* __restrict__ acol,                 // [M,4]
    int M)
{
    // As: 64 rows x 32 chunks x 16B = 32 KB (XOR-swizzled). Cs overlays.
    __shared__ __align__(16) ushortT SMEM[64 * CPITCH];
    ushortT* As = SMEM;
    ushortT* Cs = SMEM;

    const int tid  = threadIdx.x;
    const int wave = tid >> 6;       // == head
    const int lane = tid & 63;
    const int l15  = lane & 15;
    const int quad = lane >> 4;
    const int rowBase = blockIdx.x * 64;

    // ---- Prefetch B for ks=0 (independent of LDS staging).
    short8 bbuf[2][4];
    #pragma unroll
    for (int ni = 0; ni < 4; ++ni)
        bbuf[0][ni] = *(const short8*)&Bt[(wave * 64 + ni * 16 + l15) * 256 + quad * 8];

    // ---- Stage A: 64 rows x 256 cols fp32 -> bf16 swizzled LDS.
    // 4096 float4s total; 2 passes x 8 per thread (8 loads in flight/pass).
    // Layout: 16B chunk cg of row r stored at chunk (cg ^ (r&7))  [verified r4].
    #pragma unroll
    for (int pass = 0; pass < 2; ++pass) {
        float4 v[8];
        #pragma unroll
        for (int i = 0; i < 8; ++i) {
            int id  = pass * 2048 + i * 256 + tid;   // flat float4 index
            int row = id >> 6;                        // 64 float4 per row
            int c4  = id & 63;
            int gr  = rowBase + row; if (gr > M - 1) gr = M - 1;
            v[i] = *(const float4*)&feat[(size_t)gr * 256 + c4 * 4];
        }
        #pragma unroll
        for (int i = 0; i < 8; ++i) {
            int id   = pass * 2048 + i * 256 + tid;
            int row  = id >> 6;
            int c4   = id & 63;
            int cg   = c4 >> 1;                       // 16B chunk col (0..31)
            int half = c4 & 1;
            uint2 w = make_uint2(cvt2(v[i].x, v[i].y), cvt2(v[i].z, v[i].w));
            *(uint2*)&As[row * 256 + ((cg ^ (row & 7)) << 3) + half * 4] = w;
        }
    }

    __syncthreads();

    floatx4 acc[4][4] = {};

    #pragma unroll
    for (int ks = 0; ks < 8; ++ks) {
        if (ks < 7) {
            #pragma unroll
            for (int ni = 0; ni < 4; ++ni)
                bbuf[(ks + 1) & 1][ni] = *(const short8*)
                    &Bt[(wave * 64 + ni * 16 + l15) * 256 + (ks + 1) * 32 + quad * 8];
        }
        short8 af[4];
        #pragma unroll
        for (int mi = 0; mi < 4; ++mi) {
            int row = mi * 16 + l15;
            int q   = ks * 4 + quad;
            int cst = q ^ (row & 7);
            af[mi] = *(const short8*)&As[row * 256 + cst * 8];
        }
        #pragma unroll
        for (int mi = 0; mi < 4; ++mi)
            #pragma unroll
            for (int ni = 0; ni < 4; ++ni)
                acc[mi][ni] = __builtin_amdgcn_mfma_f32_16x16x32_bf16(
                    af[mi], bbuf[ks & 1][ni], acc[mi][ni], 0, 0, 0);
    }

    // ---- Epilogue A: attention scores (wave == head).
    float al[4], ar[4];
    #pragma unroll
    for (int ni = 0; ni < 4; ++ni) {
        al[ni] = attn_l[wave * 64 + ni * 16 + l15];
        ar[ni] = attn_r[wave * 64 + ni * 16 + l15];
    }
    #pragma unroll
    for (int mi = 0; mi < 4; ++mi) {
        #pragma unroll
        for (int reg = 0; reg < 4; ++reg) {
            float pl = 0.f, pr = 0.f;
            #pragma unroll
            for (int ni = 0; ni < 4; ++ni) {
                pl = fmaf(acc[mi][ni][reg], al[ni], pl);
                pr = fmaf(acc[mi][ni][reg], ar[ni], pr);
            }
            #pragma unroll
            for (int off = 8; off >= 1; off >>= 1) {
                pl += __shfl_xor(pl, off, 64);   // stays within 16-lane quad
                pr += __shfl_xor(pr, off, 64);
            }
            if (l15 == 0) {
                int gr = rowBase + mi * 16 + quad * 4 + reg;
                if (gr < M) {
                    arow[gr * NUM_HEADS + wave] = pl;
                    acol[gr * NUM_HEADS + wave] = pr;
                }
            }
        }
    }

    __syncthreads();   // all As reads complete before Cs overlay

    // ---- Epilogue B: h -> bf16, coalesced row-major store via LDS transpose.
    #pragma unroll
    for (int mi = 0; mi < 4; ++mi)
        #pragma unroll
        for (int ni = 0; ni < 4; ++ni)
            #pragma unroll
            for (int reg = 0; reg < 4; ++reg)
                Cs[(mi * 16 + quad * 4 + reg) * CPITCH + wave * 64 + ni * 16 + l15] =
                    f2bf(acc[mi][ni][reg]);
    __syncthreads();

    #pragma unroll
    for (int i = 0; i < 8; ++i) {
        int f  = tid + 256 * i;
        int r  = f >> 5;
        int c8 = (f & 31) << 3;
        int gr = rowBase + r;
        if (gr < M) {
            uint4 v = *(const uint4*)&Cs[r * CPITCH + c8];
            *(uint4*)&Hb[(size_t)gr * HF + c8] = v;
        }
    }
}

// ---------------------------------------------------------------------------
// Kernel 2 (v5): ONE WAVE PER NODE, DUAL-EDGE uint4 GATHER with EXPLICIT
// 8-DEEP MLP.  Change vs v4: all 8 gather loads are issued as one batch
// (shfls hoisted, loads into a statically-indexed uint4[8], sched_barrier
// pins the batch above the FMA block).  v4's VGPR_Count=44 showed the
// compiler was serializing the gather into ~3-4 memory round-trips; this
// trades VGPRs (~90) for single-round-trip memory-level parallelism.
// Softmax phase and output mapping unchanged (verified in v4).
// ---------------------------------------------------------------------------
__global__ __launch_bounds__(256) void gat_aggregate5(
    const ushortT* __restrict__ Hb,          // bf16 [N,256]
    const float* __restrict__ arow,          // [N,4]
    const float* __restrict__ acol,          // [N,4]
    const int* __restrict__ col_ind,         // [N*16]
    float* __restrict__ out,                 // [N,256] fp32
    int N)
{
    const int tid  = threadIdx.x;
    const int wave = tid >> 6;
    const int lane = tid & 63;
    const int n    = blockIdx.x * 4 + wave;
    if (n >= N) return;

    // ---- Softmax phase: lane = head(hd16)*16 + edge(j16)  [unchanged].
    const int j16  = lane & 15;
    const int hd16 = lane >> 4;

    int   src_e = col_ind[n * DEG + j16];
    float e = arow[n * NUM_HEADS + hd16] + acol[src_e * NUM_HEADS + hd16];
    e = (e > 0.f) ? e : NEG_SLOPE * e;

    float m = e;
    #pragma unroll
    for (int off = 8; off >= 1; off >>= 1)
        m = fmaxf(m, __shfl_xor(m, off, 16));
    float ex = __expf(e - m);
    float s = ex;
    #pragma unroll
    for (int off = 8; off >= 1; off >>= 1)
        s += __shfl_xor(s, off, 16);
    float alpha = ex / s;                  // alpha[head=hd16][edge=j16]

    // ---- Aggregation phase: dual-edge, explicit 8-deep load batch.
    // Lane covers feats l32*8 .. l32*8+7  (head = l32>>3).
    // half 0 accumulates even edges, half 1 odd edges; combine at the end.
    const int l32     = lane & 31;
    const int half    = lane >> 5;
    const int headSel = (l32 >> 3) << 4;   // head*16, for alpha bpermute

    // 1) all cross-lane pulls first (ds_bpermute, lgkm pipe)
    int   sj[8];
    float av[8];
    #pragma unroll
    for (int j = 0; j < 8; ++j) {
        int ep = (j << 1) + half;                     // edge 0..15
        sj[j] = __shfl(src_e, ep, 64);                // col_ind[n*16+ep]
        av[j] = __shfl(alpha, headSel + ep, 64);      // alpha[head][ep]
    }

    // 2) all 8 gather loads issued back-to-back (16 B/lane each)
    uint4 v[8];
    #pragma unroll
    for (int j = 0; j < 8; ++j)
        v[j] = *(const uint4*)&Hb[(size_t)sj[j] * HF + l32 * 8];

    // pin: loads may not sink below, FMAs may not hoist above
    __builtin_amdgcn_sched_barrier(0);

    // 3) FMA block (consumes v[j] in issue order -> overlapped vmcnt waits)
    float acc[8] = {};
    #pragma unroll
    for (int j = 0; j < 8; ++j) {
        acc[0] = fmaf(av[j], bf_lo(v[j].x), acc[0]);
        acc[1] = fmaf(av[j], bf_hi(v[j].x), acc[1]);
        acc[2] = fmaf(av[j], bf_lo(v[j].y), acc[2]);
        acc[3] = fmaf(av[j], bf_hi(v[j].y), acc[3]);
        acc[4] = fmaf(av[j], bf_lo(v[j].z), acc[4]);
        acc[5] = fmaf(av[j], bf_hi(v[j].z), acc[5]);
        acc[6] = fmaf(av[j], bf_lo(v[j].w), acc[6]);
        acc[7] = fmaf(av[j], bf_hi(v[j].w), acc[7]);
    }

    // Combine even/odd halves: after xor-add both halves hold full sums.
    #pragma unroll
    for (int i = 0; i < 8; ++i)
        acc[i] += __shfl_xor(acc[i], 32, 64);

    // Store: lane (l32, half) writes feats l32*8 + half*4 .. +3.
    // Static indexing only (avoid runtime-indexed array -> scratch).
    float4 o;
    if (half == 0) o = make_float4(acc[0], acc[1], acc[2], acc[3]);
    else           o = make_float4(acc[4], acc[5], acc[6], acc[7]);
    *(float4*)&out[(size_t)n * HF + l32 * 8 + half * 4] = o;
}

// ---------------------------------------------------------------------------
extern "C" void kernel_launch(void* const* d_in, const int* in_sizes, int n_in,
                              void* d_out, int out_size, void* d_ws, size_t ws_size,
                              hipStream_t stream) {
    // Inputs: row_ptr, col_ind, col_ptr, row_ind, feat, W, attn_l, attn_r
    const int*   col_ind = (const int*)  d_in[1];
    const float* feat    = (const float*)d_in[4];
    const float* W       = (const float*)d_in[5];
    const float* attn_l  = (const float*)d_in[6];
    const float* attn_r  = (const float*)d_in[7];
    float* out = (float*)d_out;

    const int N = in_sizes[0] - 1;   // 50000

    // ws: Hb bf16 [N*256] | arow f32 [N*4] | acol f32 [N*4] | Wt bf16 [64K]
    ushortT* Hb   = (ushortT*)d_ws;
    float*   arow = (float*)(Hb + (size_t)N * HF);
    float*   acol = arow + (size_t)N * NUM_HEADS;
    ushortT* Wt   = (ushortT*)(acol + (size_t)N * NUM_HEADS);

    conv_wt<<<256, 256, 0, stream>>>(W, Wt);

    dim3 ggrid((N + 63) / 64);
    gat_gemm_fused<<<ggrid, 256, 0, stream>>>(feat, Wt, attn_l, attn_r,
                                              Hb, arow, acol, N);

    gat_aggregate5<<<(N + 3) / 4, 256, 0, stream>>>(Hb, arow, acol, col_ind, out, N);
}